// Round 1
// baseline (444.399 us; speedup 1.0000x reference)
//
#include <hip/hip_runtime.h>
#include <stdint.h>

#define B_ 2
#define S_ 2048
#define D_ 1024
#define H_ 16
#define HD_ 64

typedef unsigned short ushort_t;
typedef __bf16 bf16x8_t __attribute__((ext_vector_type(8)));
typedef unsigned short us8 __attribute__((ext_vector_type(8)));
typedef float f32x4 __attribute__((ext_vector_type(4)));

using gq_t = const unsigned int __attribute__((address_space(1)));
using lq_t = unsigned int __attribute__((address_space(3)));

__device__ __forceinline__ unsigned short f2bf(float f) {
    unsigned u = __builtin_bit_cast(unsigned, f);
    u += 0x7fffu + ((u >> 16) & 1u);
    return (unsigned short)(u >> 16);
}
__device__ __forceinline__ float bf2f(unsigned short h) {
    unsigned u = ((unsigned)h) << 16;
    return __builtin_bit_cast(float, u);
}
__device__ __forceinline__ f32x4 mfma16(us8 a, us8 b, f32x4 c) {
    return __builtin_amdgcn_mfma_f32_16x16x32_bf16(
        __builtin_bit_cast(bf16x8_t, a), __builtin_bit_cast(bf16x8_t, b), c, 0, 0, 0);
}
__device__ __forceinline__ void gload16(const void* g, void* l) {
    __builtin_amdgcn_global_load_lds((gq_t*)g, (lq_t*)l, 16, 0, 0);
}

// ---------------- convert X f32 -> bf16 ----------------
__global__ __launch_bounds__(256) void k_convert_x(const float* __restrict__ X,
                                                   ushort_t* __restrict__ Xb) {
    int i = (blockIdx.x * 256 + threadIdx.x) * 4;
    float4 v = *reinterpret_cast<const float4*>(X + i);
    ushort4 o;
    o.x = f2bf(v.x); o.y = f2bf(v.y); o.z = f2bf(v.z); o.w = f2bf(v.w);
    *reinterpret_cast<ushort4*>(Xb + i) = o;
}

// ---------------- transpose W (K=1024 rows x N cols f32) -> Bt[n][k] bf16 ----------------
__global__ __launch_bounds__(256) void k_transpose_w(const float* __restrict__ W,
                                                     ushort_t* __restrict__ Bt,
                                                     int N, int n_base) {
    __shared__ float lds[64 * 65];
    int n0 = blockIdx.x * 64, k0 = blockIdx.y * 64;
    int t = threadIdx.x;
#pragma unroll
    for (int i = 0; i < 16; i++) {
        int idx = i * 256 + t;
        int r = idx >> 6, c = idx & 63;
        lds[c * 65 + r] = W[(size_t)(k0 + r) * N + (n0 + c)];
    }
    __syncthreads();
#pragma unroll
    for (int i = 0; i < 16; i++) {
        int idx = i * 256 + t;
        int nn = idx >> 6, k = idx & 63;
        Bt[(size_t)(n_base + n0 + nn) * 1024 + (k0 + k)] = f2bf(lds[nn * 65 + k]);
    }
}

// ---------------- shared 128x128x(K=1024) bf16 MFMA GEMM core ----------------
__device__ __forceinline__ void gemm_tile(const ushort_t* __restrict__ A,
                                          const ushort_t* __restrict__ Bt,
                                          int m0, int n0,
                                          ushort_t* ldsA, ushort_t* ldsB,
                                          f32x4 acc[4][4]) {
    const int K = 1024;
    int t = threadIdx.x;
    int w = t >> 6, l = t & 63;
    int wr = (w >> 1) * 64, wc = (w & 1) * 64;
    int lo16 = l & 15, lg = l >> 4;
#pragma unroll
    for (int m = 0; m < 4; m++)
#pragma unroll
        for (int n = 0; n < 4; n++) acc[m][n] = f32x4{0.f, 0.f, 0.f, 0.f};

    for (int k0 = 0; k0 < K; k0 += 64) {
#pragma unroll
        for (int i = 0; i < 4; i++) {
            int c = i * 256 + t;
            int row = c >> 3, co = (c & 7) * 8;
            gload16(A + (size_t)(m0 + row) * K + k0 + co, ldsA + (size_t)c * 8);
            gload16(Bt + (size_t)(n0 + row) * K + k0 + co, ldsB + (size_t)c * 8);
        }
        __syncthreads();
#pragma unroll
        for (int kk = 0; kk < 2; kk++) {
            us8 af[4], bfr[4];
#pragma unroll
            for (int m = 0; m < 4; m++)
                af[m] = *(const us8*)(ldsA + (wr + m * 16 + lo16) * 64 + kk * 32 + lg * 8);
#pragma unroll
            for (int n = 0; n < 4; n++)
                bfr[n] = *(const us8*)(ldsB + (wc + n * 16 + lo16) * 64 + kk * 32 + lg * 8);
#pragma unroll
            for (int m = 0; m < 4; m++)
#pragma unroll
                for (int n = 0; n < 4; n++)
                    acc[m][n] = mfma16(af[m], bfr[n], acc[m][n]);
        }
        __syncthreads();
    }
}

// ---------------- QKV projection GEMM with head-scatter epilogue ----------------
__global__ __launch_bounds__(256) void k_gemm_qkv(const ushort_t* __restrict__ Xb,
                                                  const ushort_t* __restrict__ Wt,
                                                  ushort_t* __restrict__ Q1, ushort_t* __restrict__ Q2,
                                                  ushort_t* __restrict__ K1, ushort_t* __restrict__ K2,
                                                  ushort_t* __restrict__ Vr) {
    __shared__ __align__(16) ushort_t ldsA[128 * 64];
    __shared__ __align__(16) ushort_t ldsB[128 * 64];
    f32x4 acc[4][4];
    int m0 = blockIdx.y * 128, n0 = blockIdx.x * 128;
    gemm_tile(Xb, Wt, m0, n0, ldsA, ldsB, acc);
    int t = threadIdx.x, w = t >> 6, l = t & 63;
    int wr = (w >> 1) * 64, wc = (w & 1) * 64, lo16 = l & 15, lg = l >> 4;
#pragma unroll
    for (int m = 0; m < 4; m++) {
#pragma unroll
        for (int n = 0; n < 4; n++) {
#pragma unroll
            for (int r = 0; r < 4; r++) {
                int row = m0 + wr + m * 16 + lg * 4 + r;   // 0..4095 = b*S + s
                int col = n0 + wc + n * 16 + lo16;         // 0..5119
                int b = row >> 11, s = row & 2047;
                ushort_t v = f2bf(acc[m][n][r]);
                if (col < 2048) {
                    int h = col >> 7, dd = col & 127;
                    ushort_t* dst = (dd < 64) ? Q1 : Q2;
                    dst[(((size_t)(b * H_ + h)) * S_ + s) * HD_ + (dd & 63)] = v;
                } else if (col < 4096) {
                    int c2 = col - 2048;
                    int h = c2 >> 7, dd = c2 & 127;
                    ushort_t* dst = (dd < 64) ? K1 : K2;
                    dst[(((size_t)(b * H_ + h)) * S_ + s) * HD_ + (dd & 63)] = v;
                } else {
                    int c2 = col - 4096;
                    int h = c2 >> 6, d = c2 & 63;
                    Vr[(((size_t)(b * H_ + h)) * S_ + s) * HD_ + d] = v;
                }
            }
        }
    }
}

// ---------------- output GEMM: Yb @ Wo -> f32 ----------------
__global__ __launch_bounds__(256) void k_gemm_out(const ushort_t* __restrict__ Yb,
                                                  const ushort_t* __restrict__ Wot,
                                                  float* __restrict__ Out) {
    __shared__ __align__(16) ushort_t ldsA[128 * 64];
    __shared__ __align__(16) ushort_t ldsB[128 * 64];
    f32x4 acc[4][4];
    int m0 = blockIdx.y * 128, n0 = blockIdx.x * 128;
    gemm_tile(Yb, Wot, m0, n0, ldsA, ldsB, acc);
    int t = threadIdx.x, w = t >> 6, l = t & 63;
    int wr = (w >> 1) * 64, wc = (w & 1) * 64, lo16 = l & 15, lg = l >> 4;
#pragma unroll
    for (int m = 0; m < 4; m++)
#pragma unroll
        for (int n = 0; n < 4; n++)
#pragma unroll
            for (int r = 0; r < 4; r++)
                Out[(size_t)(m0 + wr + m * 16 + lg * 4 + r) * 1024 + (n0 + wc + n * 16 + lo16)] =
                    acc[m][n][r];
}

// ---------------- V transpose per head: [S][64] -> [64][S] ----------------
__global__ __launch_bounds__(256) void k_transpose_v(const ushort_t* __restrict__ Vr,
                                                     ushort_t* __restrict__ Vt) {
    __shared__ ushort_t lds[64 * 72];
    int bh = blockIdx.x, s0 = blockIdx.y * 64;
    const ushort_t* src = Vr + ((size_t)bh * S_ + s0) * HD_;
    ushort_t* dst = Vt + (size_t)bh * HD_ * S_ + s0;
    int t = threadIdx.x;
#pragma unroll
    for (int i = 0; i < 16; i++) {
        int idx = i * 256 + t;
        int s = idx >> 6, d = idx & 63;
        lds[d * 72 + s] = src[(size_t)s * 64 + d];
    }
    __syncthreads();
#pragma unroll
    for (int i = 0; i < 16; i++) {
        int idx = i * 256 + t;
        int d = idx >> 6, s = idx & 63;
        dst[(size_t)d * S_ + s] = lds[d * 72 + s];
    }
}

// ---------------- fused dual flash attention + memory term + stats ----------------
__global__ __launch_bounds__(256) void k_attn(
    const ushort_t* __restrict__ Q1g, const ushort_t* __restrict__ Q2g,
    const ushort_t* __restrict__ K1g, const ushort_t* __restrict__ K2g,
    const ushort_t* __restrict__ Vtg, const float* __restrict__ mask,
    const float* __restrict__ lam_q1, const float* __restrict__ lam_q2,
    const float* __restrict__ lam_k1, const float* __restrict__ lam_k2,
    const float* __restrict__ mgate, const float* __restrict__ memp,
    const float* __restrict__ zp, float* __restrict__ Oatt, float* __restrict__ stats) {
    __shared__ __align__(16) ushort_t smem[64 * 64 * 3 + 2 * 4 * 16 * 72];
    __shared__ float ldsMaskAdj[64];
    ushort_t* ldsK1 = smem;
    ushort_t* ldsK2 = smem + 4096;
    ushort_t* ldsV  = smem + 8192;
    ushort_t* ldsP1 = smem + 12288;
    ushort_t* ldsP2 = smem + 12288 + 4608;
    ushort_t* ldsM  = smem + 12288;   // overlay onto P region (epilogue only)

    int qt = blockIdx.x, bh = blockIdx.y;
    int b = bh >> 4, h = bh & 15;
    int q0 = qt * 64;
    int t = threadIdx.x, w = t >> 6, l = t & 63;
    int lo16 = l & 15, lg = l >> 4;

    const ushort_t* Q1 = Q1g + (size_t)bh * S_ * HD_;
    const ushort_t* Q2 = Q2g + (size_t)bh * S_ * HD_;
    const ushort_t* K1 = K1g + (size_t)bh * S_ * HD_;
    const ushort_t* K2 = K2g + (size_t)bh * S_ * HD_;
    const ushort_t* Vt = Vtg + (size_t)bh * HD_ * S_;

    // preload Q fragments (A-operand layout: row = lane&15, k = (lane>>4)*8+j)
    int qrowA = q0 + w * 16 + lo16;
    us8 q1f[2], q2f[2];
    q1f[0] = *(const us8*)(Q1 + (size_t)qrowA * HD_ + lg * 8);
    q1f[1] = *(const us8*)(Q1 + (size_t)qrowA * HD_ + 32 + lg * 8);
    q2f[0] = *(const us8*)(Q2 + (size_t)qrowA * HD_ + lg * 8);
    q2f[1] = *(const us8*)(Q2 + (size_t)qrowA * HD_ + 32 + lg * 8);

    float la = 0.f, lb = 0.f;
    for (int i = 0; i < HD_; i++) { la += lam_q1[i] * lam_k1[i]; lb += lam_q2[i] * lam_k2[i]; }
    float lam = __expf(la) - __expf(lb) + 0.8f;

    float m1[4], l1[4], m2[4], l2[4];
    f32x4 o1[4], o2[4];
#pragma unroll
    for (int r = 0; r < 4; r++) { m1[r] = -1e30f; l1[r] = 0.f; m2[r] = -1e30f; l2[r] = 0.f; }
#pragma unroll
    for (int n = 0; n < 4; n++) { o1[n] = f32x4{0, 0, 0, 0}; o2[n] = f32x4{0, 0, 0, 0}; }

    float slope = exp2f(-0.5f * (float)(h + 1));
    const float scale = 0.125f;
    ushort_t* P1w = ldsP1 + w * (16 * 72);
    ushort_t* P2w = ldsP2 + w * (16 * 72);
    int qrow = q0 + w * 16 + lg * 4;

    auto softmax_step = [&](f32x4(&sarr)[4], float(&mm)[4], float(&ll)[4], f32x4(&oo)[4],
                            ushort_t* Pw, int kv0) {
        float mt[4] = {-1e30f, -1e30f, -1e30f, -1e30f};
#pragma unroll
        for (int n = 0; n < 4; n++) {
            int kv = kv0 + n * 16 + lo16;
            float padv = ldsMaskAdj[n * 16 + lo16];
#pragma unroll
            for (int r = 0; r < 4; r++) {
                int q = qrow + r;
                float sv = sarr[n][r] * scale - slope * (float)(q - kv) + padv;
                if (kv > q) sv = -1e9f;
                sarr[n][r] = sv;
                mt[r] = fmaxf(mt[r], sv);
            }
        }
#pragma unroll
        for (int r = 0; r < 4; r++) {
#pragma unroll
            for (int off = 1; off < 16; off <<= 1) mt[r] = fmaxf(mt[r], __shfl_xor(mt[r], off));
            float mn = fmaxf(mm[r], mt[r]);
            float alpha = __expf(mm[r] - mn);
            mm[r] = mn;
            ll[r] *= alpha;
#pragma unroll
            for (int n = 0; n < 4; n++) oo[n][r] *= alpha;
        }
        float rs[4] = {0, 0, 0, 0};
#pragma unroll
        for (int n = 0; n < 4; n++) {
#pragma unroll
            for (int r = 0; r < 4; r++) {
                float p = __expf(sarr[n][r] - mm[r]);
                rs[r] += p;
                Pw[(lg * 4 + r) * 72 + n * 16 + lo16] = f2bf(p);
            }
        }
#pragma unroll
        for (int r = 0; r < 4; r++) {
#pragma unroll
            for (int off = 1; off < 16; off <<= 1) rs[r] += __shfl_xor(rs[r], off);
            ll[r] += rs[r];
        }
    };

    int nsteps = qt + 1;
    for (int step = 0; step < nsteps; ++step) {
        int kv0 = step * 64;
#pragma unroll
        for (int i = 0; i < 2; i++) {
            int c = i * 256 + t, row = c >> 3, co = (c & 7) * 8;
            gload16(K1 + (size_t)(kv0 + row) * HD_ + co, ldsK1 + c * 8);
            gload16(K2 + (size_t)(kv0 + row) * HD_ + co, ldsK2 + c * 8);
            gload16(Vt + (size_t)row * S_ + kv0 + co, ldsV + c * 8);
        }
        if (t < 64) ldsMaskAdj[t] = (1.f - mask[(size_t)b * S_ + kv0 + t]) * -1e9f;
        __syncthreads();

        f32x4 s1[4], s2[4];
#pragma unroll
        for (int n = 0; n < 4; n++) { s1[n] = f32x4{0, 0, 0, 0}; s2[n] = f32x4{0, 0, 0, 0}; }
#pragma unroll
        for (int kk = 0; kk < 2; kk++) {
#pragma unroll
            for (int n = 0; n < 4; n++) {
                us8 kf1 = *(const us8*)(ldsK1 + (n * 16 + lo16) * 64 + kk * 32 + lg * 8);
                us8 kf2 = *(const us8*)(ldsK2 + (n * 16 + lo16) * 64 + kk * 32 + lg * 8);
                s1[n] = mfma16(q1f[kk], kf1, s1[n]);
                s2[n] = mfma16(q2f[kk], kf2, s2[n]);
            }
        }
        softmax_step(s1, m1, l1, o1, P1w, kv0);
        softmax_step(s2, m2, l2, o2, P2w, kv0);
        __syncthreads();
#pragma unroll
        for (int kk = 0; kk < 2; kk++) {
            us8 pf1 = *(const us8*)(P1w + lo16 * 72 + kk * 32 + lg * 8);
            us8 pf2 = *(const us8*)(P2w + lo16 * 72 + kk * 32 + lg * 8);
#pragma unroll
            for (int n = 0; n < 4; n++) {
                us8 vf = *(const us8*)(ldsV + (n * 16 + lo16) * 64 + kk * 32 + lg * 8);
                o1[n] = mfma16(pf1, vf, o1[n]);
                o2[n] = mfma16(pf2, vf, o2[n]);
            }
        }
        __syncthreads();
    }

    // ---- epilogue: sigma@mem, sigma@z, gate combine, stats ----
    for (int i = t; i < 80 * 64; i += 256) {
        int n = i >> 6, kd = i & 63;
        float v = 0.f;
        if (n < 64) v = memp[((size_t)h * 64 + kd) * 64 + n];
        else if (n == 64) v = zp[h * 64 + kd];
        ldsM[i] = f2bf(v);
    }
    __syncthreads();

    us8 sf[2];
#pragma unroll
    for (int kk = 0; kk < 2; kk++) {
#pragma unroll
        for (int j = 0; j < 8; j++) {
            float x = bf2f(q1f[kk][j]);
            float e = (x > 0.f) ? x : (__expf(x) - 1.f);
            sf[kk][j] = f2bf(e + 1.f);
        }
    }
    f32x4 mv[5];
#pragma unroll
    for (int n = 0; n < 5; n++) mv[n] = f32x4{0, 0, 0, 0};
#pragma unroll
    for (int kk = 0; kk < 2; kk++)
#pragma unroll
        for (int n = 0; n < 5; n++) {
            us8 mb = *(const us8*)(ldsM + (n * 16 + lo16) * 64 + kk * 32 + lg * 8);
            mv[n] = mfma16(sf[kk], mb, mv[n]);
        }
    float denom[4];
#pragma unroll
    for (int r = 0; r < 4; r++) denom[r] = __shfl(mv[4][r], lg * 16);

    float gsum = 0.f, gsq = 0.f;
#pragma unroll
    for (int n = 0; n < 4; n++) {
        int d = n * 16 + lo16;
        float gate = 1.f / (1.f + __expf(-mgate[h * HD_ + d]));
#pragma unroll
        for (int r = 0; r < 4; r++) {
            int q = q0 + w * 16 + lg * 4 + r;
            float dmv = mv[n][r] / denom[r];
            float oa = o1[n][r] / l1[r] - lam * (o2[n][r] / l2[r]);
            float val = gate * dmv + (1.f - gate) * oa;
            Oatt[((size_t)bh * S_ + q) * HD_ + d] = val;
            gsum += val;
            gsq += val * val;
        }
    }
#pragma unroll
    for (int off = 1; off < 64; off <<= 1) {
        gsum += __shfl_xor(gsum, off);
        gsq += __shfl_xor(gsq, off);
    }
    if (l == 0) {
        atomicAdd(&stats[bh * 2 + 0], gsum);
        atomicAdd(&stats[bh * 2 + 1], gsq);
    }
}

// ---------------- groupnorm normalize -> Yb bf16 [B][S][D] (x 0.2) ----------------
__global__ __launch_bounds__(256) void k_norm(const float* __restrict__ Oatt,
                                              const float* __restrict__ stats,
                                              const float* __restrict__ gw,
                                              const float* __restrict__ gb,
                                              ushort_t* __restrict__ Yb) {
    int i4 = (blockIdx.x * 256 + threadIdx.x) * 4;
    int bh = i4 >> 17;
    int rest = i4 & 131071;
    int s = rest >> 6, d = rest & 63;
    int b = bh >> 4, h = bh & 15;
    float mu = stats[bh * 2] * (1.f / 131072.f);
    float var = stats[bh * 2 + 1] * (1.f / 131072.f) - mu * mu;
    float rstd = rsqrtf(var + 1e-5f);
    float4 v = *reinterpret_cast<const float4*>(Oatt + i4);
    int c = h * 64 + d;
    ushort4 o;
    o.x = f2bf(((v.x - mu) * rstd * gw[c + 0] + gb[c + 0]) * 0.2f);
    o.y = f2bf(((v.y - mu) * rstd * gw[c + 1] + gb[c + 1]) * 0.2f);
    o.z = f2bf(((v.z - mu) * rstd * gw[c + 2] + gb[c + 2]) * 0.2f);
    o.w = f2bf(((v.w - mu) * rstd * gw[c + 3] + gb[c + 3]) * 0.2f);
    *reinterpret_cast<ushort4*>(Yb + ((size_t)(b * S_ + s)) * 1024 + c) = o;
}

extern "C" void kernel_launch(void* const* d_in, const int* in_sizes, int n_in,
                              void* d_out, int out_size, void* d_ws, size_t ws_size,
                              hipStream_t stream) {
    const float* X      = (const float*)d_in[0];
    const float* mask   = (const float*)d_in[1];
    const float* Wq     = (const float*)d_in[2];
    const float* Wk     = (const float*)d_in[3];
    const float* Wv     = (const float*)d_in[4];
    const float* Wo     = (const float*)d_in[5];
    const float* lam_q1 = (const float*)d_in[6];
    const float* lam_q2 = (const float*)d_in[7];
    const float* lam_k1 = (const float*)d_in[8];
    const float* lam_k2 = (const float*)d_in[9];
    const float* gw     = (const float*)d_in[10];
    const float* gb     = (const float*)d_in[11];
    const float* mgate  = (const float*)d_in[12];
    const float* memp   = (const float*)d_in[13];
    const float* zp     = (const float*)d_in[14];

    char* p = (char*)d_ws;
    auto alloc = [&](size_t bytes) -> char* {
        char* r = p;
        p += (bytes + 255) & ~(size_t)255;
        return r;
    };
    ushort_t* Xb  = (ushort_t*)alloc((size_t)4096 * 1024 * 2);
    ushort_t* Wt  = (ushort_t*)alloc((size_t)5120 * 1024 * 2);
    ushort_t* Wot = (ushort_t*)alloc((size_t)1024 * 1024 * 2);
    ushort_t* Q1  = (ushort_t*)alloc((size_t)B_ * H_ * S_ * HD_ * 2);
    ushort_t* Q2  = (ushort_t*)alloc((size_t)B_ * H_ * S_ * HD_ * 2);
    ushort_t* K1  = (ushort_t*)alloc((size_t)B_ * H_ * S_ * HD_ * 2);
    ushort_t* K2  = (ushort_t*)alloc((size_t)B_ * H_ * S_ * HD_ * 2);
    ushort_t* Vr  = (ushort_t*)alloc((size_t)B_ * H_ * S_ * HD_ * 2);
    ushort_t* Vt  = (ushort_t*)alloc((size_t)B_ * H_ * S_ * HD_ * 2);
    float*    Oat = (float*)alloc((size_t)B_ * H_ * S_ * HD_ * 4);
    ushort_t* Yb  = (ushort_t*)alloc((size_t)4096 * 1024 * 2);
    float*    st  = (float*)alloc(256);

    k_convert_x<<<4096, 256, 0, stream>>>(X, Xb);
    k_transpose_w<<<dim3(32, 16), 256, 0, stream>>>(Wq, Wt, 2048, 0);
    k_transpose_w<<<dim3(32, 16), 256, 0, stream>>>(Wk, Wt, 2048, 2048);
    k_transpose_w<<<dim3(16, 16), 256, 0, stream>>>(Wv, Wt, 1024, 4096);
    k_transpose_w<<<dim3(16, 16), 256, 0, stream>>>(Wo, Wot, 1024, 0);
    k_gemm_qkv<<<dim3(40, 32), 256, 0, stream>>>(Xb, Wt, Q1, Q2, K1, K2, Vr);
    k_transpose_v<<<dim3(32, 32), 256, 0, stream>>>(Vr, Vt);
    hipMemsetAsync(st, 0, 64 * sizeof(float), stream);
    k_attn<<<dim3(32, 32), 256, 0, stream>>>(Q1, Q2, K1, K2, Vt, mask, lam_q1, lam_q2,
                                             lam_k1, lam_k2, mgate, memp, zp, Oat, st);
    k_norm<<<4096, 256, 0, stream>>>(Oat, st, gw, gb, Yb);
    k_gemm_out<<<dim3(8, 32), 256, 0, stream>>>(Yb, Wot, (float*)d_out);
}